// Round 1
// baseline (87.605 us; speedup 1.0000x reference)
//
#include <hip/hip_runtime.h>

// MinibatchDiscrimination: out[i,k] = sum_j exp(-sum_d |x[i,k,d]-x[j,k,d]|)
// where x = inputs @ T, inputs [512,1024] f32, T [1024,500] f32, x -> [512,100,5].
//
// Fused single kernel: one block per k (grid=100), 1024 threads.
//   Phase A: thread t=(i, h) computes partial 5-dot over f in [h*512,(h+1)*512).
//            T loads are wave-uniform (k, ff, readfirstlane(h)) -> scalar s_load.
//   Fold:    x[i][d] = partial(h=0) + partial(h=1) in LDS.
//   Phase B: thread t=(i, jg) accumulates exp(-L1) over 256 j's; x_j read from
//            LDS with uniform address (broadcast, conflict-free).
//   Reduce:  out[i,k] = partial(jg=0) + partial(jg=1).

#define BB 512
#define FF 1024
#define KK 100
#define DD 5
#define KD 500   // K*D

__global__ __launch_bounds__(1024, 1) void mbd_fused(
    const float* __restrict__ in, const float* __restrict__ T, float* __restrict__ out)
{
    const int k = blockIdx.x;
    const int t = threadIdx.x;
    const int i = t & (BB - 1);
    // h is uniform within each wave; readfirstlane lets the compiler prove it
    // so the T loads below become scalar (s_load) instead of per-lane VMEM.
    const int h = __builtin_amdgcn_readfirstlane(t >> 9);

    __shared__ float xk[1024][8];   // 32 KiB. rows 0..511 hold x after fold.

    // ---------------- Phase A: x[i, k, 0..4] partial dot over half the f range
    float a0 = 0.f, a1 = 0.f, a2 = 0.f, a3 = 0.f, a4 = 0.f;
    const float4* inrow = (const float4*)(in + (size_t)i * FF + (size_t)h * 512);
    const float* Tk = T + DD * k + (size_t)h * 512 * KD;

    for (int ff = 0; ff < 512; ff += 4) {
        float4 v = inrow[ff >> 2];
        const float* tp = Tk + (size_t)ff * KD;
        a0 = fmaf(v.x, tp[0], a0);
        a1 = fmaf(v.x, tp[1], a1);
        a2 = fmaf(v.x, tp[2], a2);
        a3 = fmaf(v.x, tp[3], a3);
        a4 = fmaf(v.x, tp[4], a4);
        tp += KD;
        a0 = fmaf(v.y, tp[0], a0);
        a1 = fmaf(v.y, tp[1], a1);
        a2 = fmaf(v.y, tp[2], a2);
        a3 = fmaf(v.y, tp[3], a3);
        a4 = fmaf(v.y, tp[4], a4);
        tp += KD;
        a0 = fmaf(v.z, tp[0], a0);
        a1 = fmaf(v.z, tp[1], a1);
        a2 = fmaf(v.z, tp[2], a2);
        a3 = fmaf(v.z, tp[3], a3);
        a4 = fmaf(v.z, tp[4], a4);
        tp += KD;
        a0 = fmaf(v.w, tp[0], a0);
        a1 = fmaf(v.w, tp[1], a1);
        a2 = fmaf(v.w, tp[2], a2);
        a3 = fmaf(v.w, tp[3], a3);
        a4 = fmaf(v.w, tp[4], a4);
    }
    xk[t][0] = a0; xk[t][1] = a1; xk[t][2] = a2; xk[t][3] = a3; xk[t][4] = a4;
    __syncthreads();

    // ---------------- Fold the two f-halves
    if (t < BB) {
        xk[t][0] += xk[t + BB][0];
        xk[t][1] += xk[t + BB][1];
        xk[t][2] += xk[t + BB][2];
        xk[t][3] += xk[t + BB][3];
        xk[t][4] += xk[t + BB][4];
    }
    __syncthreads();

    // ---------------- Phase B: sum_j exp(-L1(x_i, x_j)) over this thread's j half
    const int jg = t >> 9;                 // 0 or 1
    const float4 xiv = *(const float4*)&xk[i][0];
    const float xi4 = xk[i][4];
    const float NEG_LOG2E = -1.4426950408889634f;

    float s0 = 0.f, s1 = 0.f;
    const int j0 = jg << 8;
    for (int jj = 0; jj < 256; jj += 2) {
        {
            const int j = j0 + jj;
            float4 xj = *(const float4*)&xk[j][0];
            float xj4 = xk[j][4];
            float d0 = xiv.x - xj.x, d1 = xiv.y - xj.y;
            float d2 = xiv.z - xj.z, d3 = xiv.w - xj.w;
            float d4 = xi4 - xj4;
            float aa = (fabsf(d0) + fabsf(d1)) + (fabsf(d2) + fabsf(d3)) + fabsf(d4);
            s0 += __builtin_amdgcn_exp2f(NEG_LOG2E * aa);
        }
        {
            const int j = j0 + jj + 1;
            float4 xj = *(const float4*)&xk[j][0];
            float xj4 = xk[j][4];
            float d0 = xiv.x - xj.x, d1 = xiv.y - xj.y;
            float d2 = xiv.z - xj.z, d3 = xiv.w - xj.w;
            float d4 = xi4 - xj4;
            float aa = (fabsf(d0) + fabsf(d1)) + (fabsf(d2) + fabsf(d3)) + fabsf(d4);
            s1 += __builtin_amdgcn_exp2f(NEG_LOG2E * aa);
        }
    }

    // ---------------- Reduce the two j halves and store
    xk[BB + i][jg] = s0 + s1;   // rows 512..1023 are free after the fold
    __syncthreads();
    if (t < BB) {
        out[(size_t)t * KK + k] = xk[BB + t][0] + xk[BB + t][1];
    }
}

extern "C" void kernel_launch(void* const* d_in, const int* in_sizes, int n_in,
                              void* d_out, int out_size, void* d_ws, size_t ws_size,
                              hipStream_t stream) {
    const float* in = (const float*)d_in[0];   // [512, 1024]
    const float* T  = (const float*)d_in[1];   // [1024, 500]
    float* out = (float*)d_out;                // [512, 100]
    mbd_fused<<<KK, 1024, 0, stream>>>(in, T, out);
}

// Round 2
// 65.668 us; speedup vs baseline: 1.3341x; 1.3341x over previous
//
#include <hip/hip_runtime.h>

// MinibatchDiscrimination, two-phase:
//   K1: x = inputs @ T        (partial over S f-splits, into ws)
//   K2: out[i,k] = sum_j exp(-sum_d |x[i,k,d]-x[j,k,d]|)
//
// inputs [512,1024] f32, T [1024,500] f32, out [512,100] f32.

#define BB 512
#define FF 1024
#define KK 100
#define DD 5
#define KD 500
#define KDP 512   // kd padded to 512 in ws
#define IB 8      // i-rows per K1 block

// ---------------- Kernel 1: partial projection ----------------
// grid = (BB/IB, S), block = 512 (one kd per thread).
// ws layout: float xp[S][BB][KDP].
// in-row loads are wave-uniform -> scalar pipe; T loads coalesced across kd.
template <int S>
__global__ __launch_bounds__(512, 2) void mbd_proj(
    const float* __restrict__ in, const float* __restrict__ T,
    float* __restrict__ xp)
{
    const int kd = threadIdx.x;
    const int i0 = __builtin_amdgcn_readfirstlane(blockIdx.x * IB);
    const int s  = __builtin_amdgcn_readfirstlane(blockIdx.y);
    constexpr int FN = FF / S;
    const int f0 = s * FN;

    float acc[IB];
    #pragma unroll
    for (int r = 0; r < IB; ++r) acc[r] = 0.f;

    const bool active = (kd < KD);
    const float* Tp  = T + (size_t)f0 * KD + (active ? kd : 0);
    const float* inp = in + (size_t)i0 * FF + f0;

    #pragma unroll 4
    for (int f = 0; f < FN; ++f) {
        float tv = active ? Tp[(size_t)f * KD] : 0.f;
        #pragma unroll
        for (int r = 0; r < IB; ++r) {
            float iv = inp[(size_t)r * FF + f];   // uniform address -> s_load
            acc[r] = fmaf(iv, tv, acc[r]);
        }
    }

    float* op = xp + ((size_t)s * BB + i0) * KDP + kd;
    #pragma unroll
    for (int r = 0; r < IB; ++r) op[(size_t)r * KDP] = acc[r];
}

// ---------------- Kernel 2: pairwise exp-L1 ----------------
// grid = (KK, BB/64), block = 256. Wave q handles j in [q*128, q*128+128),
// lane = i_local. x_j reads are wave-uniform LDS -> broadcast, conflict-free.
template <int S>
__global__ __launch_bounds__(256, 4) void mbd_pair(
    const float* __restrict__ xp, float* __restrict__ out)
{
    const int k    = blockIdx.x;
    const int i0   = blockIdx.y * 64;
    const int t    = threadIdx.x;
    const int lane = t & 63;
    const int q    = t >> 6;        // wave id 0..3

    __shared__ float xs[BB][8];     // 16 KiB, row stride 32 B (b128-aligned)
    __shared__ float sp[4][64];

    // Fold S partials of x[j][k*5+d] into LDS for all j.
    const int kbase = k * DD;
    for (int e = t; e < BB * DD; e += 256) {
        int j = e / DD;
        int d = e - j * DD;
        float v = 0.f;
        #pragma unroll
        for (int s = 0; s < S; ++s)
            v += xp[((size_t)s * BB + j) * KDP + kbase + d];
        xs[j][d] = v;
    }
    __syncthreads();

    const int i = i0 + lane;
    const float4 xi = *(const float4*)&xs[i][0];
    const float  xi4 = xs[i][4];
    const float NEG_LOG2E = -1.4426950408889634f;

    float s0 = 0.f, s1 = 0.f;
    const int j0 = q << 7;
    #pragma unroll 2
    for (int jj = 0; jj < 128; jj += 2) {
        {
            const int j = j0 + jj;
            float4 xj = *(const float4*)&xs[j][0];
            float xj4 = xs[j][4];
            float aa = (fabsf(xi.x - xj.x) + fabsf(xi.y - xj.y))
                     + (fabsf(xi.z - xj.z) + fabsf(xi.w - xj.w))
                     + fabsf(xi4 - xj4);
            s0 += __builtin_amdgcn_exp2f(NEG_LOG2E * aa);
        }
        {
            const int j = j0 + jj + 1;
            float4 xj = *(const float4*)&xs[j][0];
            float xj4 = xs[j][4];
            float aa = (fabsf(xi.x - xj.x) + fabsf(xi.y - xj.y))
                     + (fabsf(xi.z - xj.z) + fabsf(xi.w - xj.w))
                     + fabsf(xi4 - xj4);
            s1 += __builtin_amdgcn_exp2f(NEG_LOG2E * aa);
        }
    }
    sp[q][lane] = s0 + s1;
    __syncthreads();

    if (t < 64)
        out[(size_t)(i0 + t) * KK + k] = (sp[0][t] + sp[1][t]) + (sp[2][t] + sp[3][t]);
}

// ---------------- Fallback: round-1 fused kernel (used if ws too small) ----
__global__ __launch_bounds__(1024, 1) void mbd_fused(
    const float* __restrict__ in, const float* __restrict__ T, float* __restrict__ out)
{
    const int k = blockIdx.x;
    const int t = threadIdx.x;
    const int i = t & (BB - 1);
    const int h = __builtin_amdgcn_readfirstlane(t >> 9);

    __shared__ float xk[1024][8];

    float a0 = 0.f, a1 = 0.f, a2 = 0.f, a3 = 0.f, a4 = 0.f;
    const float4* inrow = (const float4*)(in + (size_t)i * FF + (size_t)h * 512);
    const float* Tk = T + DD * k + (size_t)h * 512 * KD;

    for (int ff = 0; ff < 512; ff += 4) {
        float4 v = inrow[ff >> 2];
        const float* tp = Tk + (size_t)ff * KD;
        a0 = fmaf(v.x, tp[0], a0); a1 = fmaf(v.x, tp[1], a1); a2 = fmaf(v.x, tp[2], a2);
        a3 = fmaf(v.x, tp[3], a3); a4 = fmaf(v.x, tp[4], a4); tp += KD;
        a0 = fmaf(v.y, tp[0], a0); a1 = fmaf(v.y, tp[1], a1); a2 = fmaf(v.y, tp[2], a2);
        a3 = fmaf(v.y, tp[3], a3); a4 = fmaf(v.y, tp[4], a4); tp += KD;
        a0 = fmaf(v.z, tp[0], a0); a1 = fmaf(v.z, tp[1], a1); a2 = fmaf(v.z, tp[2], a2);
        a3 = fmaf(v.z, tp[3], a3); a4 = fmaf(v.z, tp[4], a4); tp += KD;
        a0 = fmaf(v.w, tp[0], a0); a1 = fmaf(v.w, tp[1], a1); a2 = fmaf(v.w, tp[2], a2);
        a3 = fmaf(v.w, tp[3], a3); a4 = fmaf(v.w, tp[4], a4);
    }
    xk[t][0] = a0; xk[t][1] = a1; xk[t][2] = a2; xk[t][3] = a3; xk[t][4] = a4;
    __syncthreads();

    if (t < BB) {
        xk[t][0] += xk[t + BB][0]; xk[t][1] += xk[t + BB][1]; xk[t][2] += xk[t + BB][2];
        xk[t][3] += xk[t + BB][3]; xk[t][4] += xk[t + BB][4];
    }
    __syncthreads();

    const int jg = t >> 9;
    const float4 xiv = *(const float4*)&xk[i][0];
    const float xi4 = xk[i][4];
    const float NEG_LOG2E = -1.4426950408889634f;

    float s0 = 0.f, s1 = 0.f;
    const int j0 = jg << 8;
    for (int jj = 0; jj < 256; jj += 2) {
        {
            const int j = j0 + jj;
            float4 xj = *(const float4*)&xk[j][0];
            float xj4 = xk[j][4];
            float aa = (fabsf(xiv.x - xj.x) + fabsf(xiv.y - xj.y))
                     + (fabsf(xiv.z - xj.z) + fabsf(xiv.w - xj.w)) + fabsf(xi4 - xj4);
            s0 += __builtin_amdgcn_exp2f(NEG_LOG2E * aa);
        }
        {
            const int j = j0 + jj + 1;
            float4 xj = *(const float4*)&xk[j][0];
            float xj4 = xk[j][4];
            float aa = (fabsf(xiv.x - xj.x) + fabsf(xiv.y - xj.y))
                     + (fabsf(xiv.z - xj.z) + fabsf(xiv.w - xj.w)) + fabsf(xi4 - xj4);
            s1 += __builtin_amdgcn_exp2f(NEG_LOG2E * aa);
        }
    }

    xk[BB + i][jg] = s0 + s1;
    __syncthreads();
    if (t < BB)
        out[(size_t)t * KK + k] = xk[BB + t][0] + xk[BB + t][1];
}

// ---------------- launch ----------------
extern "C" void kernel_launch(void* const* d_in, const int* in_sizes, int n_in,
                              void* d_out, int out_size, void* d_ws, size_t ws_size,
                              hipStream_t stream) {
    const float* in = (const float*)d_in[0];   // [512, 1024]
    const float* T  = (const float*)d_in[1];   // [1024, 500]
    float* out = (float*)d_out;                // [512, 100]
    float* xp  = (float*)d_ws;

    const size_t slab = (size_t)BB * KDP * sizeof(float);   // 1 MiB per split
    int S = 8;
    while (S > 1 && (size_t)S * slab > ws_size) S >>= 1;

    if (ws_size < slab) {
        // not enough scratch: fused single-kernel fallback
        mbd_fused<<<KK, 1024, 0, stream>>>(in, T, out);
        return;
    }

    dim3 g1(BB / IB, S), b1(512);
    dim3 g2(KK, BB / 64), b2(256);
    switch (S) {
    case 8:
        mbd_proj<8><<<g1, b1, 0, stream>>>(in, T, xp);
        mbd_pair<8><<<g2, b2, 0, stream>>>(xp, out);
        break;
    case 4:
        mbd_proj<4><<<g1, b1, 0, stream>>>(in, T, xp);
        mbd_pair<4><<<g2, b2, 0, stream>>>(xp, out);
        break;
    case 2:
        mbd_proj<2><<<g1, b1, 0, stream>>>(in, T, xp);
        mbd_pair<2><<<g2, b2, 0, stream>>>(xp, out);
        break;
    default:
        mbd_proj<1><<<g1, b1, 0, stream>>>(in, T, xp);
        mbd_pair<1><<<g2, b2, 0, stream>>>(xp, out);
        break;
    }
}

// Round 3
// 37.805 us; speedup vs baseline: 2.3173x; 1.7370x over previous
//
#include <hip/hip_runtime.h>

// MinibatchDiscrimination, three-phase:
//   K1 proj_tile : xp[s][i][kd] partial GEMM (register-tiled fp32, split-K S=8)
//   K2 reduce_x  : x[i][kd] = sum_s xp[s][i][kd]   (coalesced float4)
//   K3 pair2k    : out[i,k] = sum_j exp(-L1(x_i,x_j))  (2 k's per block)
//
// inputs [512,1024] f32, T [1024,500] f32, out [512,100] f32.

#define BB 512
#define FF 1024
#define KK 100
#define KD 500
#define KDP 512
#define SPLITS 8
#define FN (FF / SPLITS)   // 128 f per split

// ---------------- K1: register-tiled fp32 GEMM partials ----------------
// grid (8 i-tiles, 8 kd-tiles, 8 splits), block 256.
// Tile 64i x 64kd, per-thread 4x4. LDS: A transposed [f][i], B [f][kd].
__global__ __launch_bounds__(256, 2) void proj_tile(
    const float* __restrict__ in, const float* __restrict__ T,
    float* __restrict__ xp)
{
    const int i0  = blockIdx.x * 64;
    const int kd0 = blockIdx.y * 64;
    const int s   = blockIdx.z;
    const int t   = threadIdx.x;
    const int tk  = t & 15;        // kd-quad index
    const int ti  = t >> 4;        // i-quad index

    __shared__ float Ads[16][68];  // [f][i], row 272B = 17*16B (b128-aligned)
    __shared__ float Bds[16][64];  // [f][kd]

    float acc[4][4];
    #pragma unroll
    for (int r = 0; r < 4; ++r)
        #pragma unroll
        for (int c = 0; c < 4; ++c) acc[r][c] = 0.f;

    // staging roles
    const int ia  = t >> 2;               // 0..63 : i row for A staging
    const int fqa = t & 3;                // f-quad within 16
    const int kb  = t & 63;               // kd lane for B staging
    const int frb = t >> 6;               // 0..3 : f-quad for B staging
    const int kbc = min(kd0 + kb, KD - 1);  // clamp: never read past T row end

    for (int step = 0; step < FN / 16; ++step) {
        const int fs = s * FN + step * 16;
        __syncthreads();
        // stage A (coalesced 64B-line reads along f, transpose into LDS)
        float4 av = *(const float4*)&in[(size_t)(i0 + ia) * FF + fs + fqa * 4];
        Ads[fqa * 4 + 0][ia] = av.x;
        Ads[fqa * 4 + 1][ia] = av.y;
        Ads[fqa * 4 + 2][ia] = av.z;
        Ads[fqa * 4 + 3][ia] = av.w;
        // stage B (coalesced 256B reads along kd)
        #pragma unroll
        for (int r = 0; r < 4; ++r)
            Bds[frb * 4 + r][kb] = T[(size_t)(fs + frb * 4 + r) * KD + kbc];
        __syncthreads();

        #pragma unroll
        for (int f = 0; f < 16; ++f) {
            float4 a = *(const float4*)&Ads[f][ti * 4];
            float4 b = *(const float4*)&Bds[f][tk * 4];
            float ar[4] = {a.x, a.y, a.z, a.w};
            float br[4] = {b.x, b.y, b.z, b.w};
            #pragma unroll
            for (int r = 0; r < 4; ++r)
                #pragma unroll
                for (int c = 0; c < 4; ++c)
                    acc[r][c] = fmaf(ar[r], br[c], acc[r][c]);
        }
    }

    #pragma unroll
    for (int r = 0; r < 4; ++r) {
        float4 v = {acc[r][0], acc[r][1], acc[r][2], acc[r][3]};
        *(float4*)&xp[((size_t)s * BB + i0 + ti * 4 + r) * KDP + kd0 + tk * 4] = v;
    }
}

// ---------------- K2: fold split partials, coalesced ----------------
__global__ __launch_bounds__(256) void reduce_x(
    const float* __restrict__ xp, float* __restrict__ x)
{
    const int e = blockIdx.x * 256 + threadIdx.x;   // float4 index < 65536
    const float4* xp4 = (const float4*)xp;
    float4 v = xp4[e];
    #pragma unroll
    for (int s = 1; s < SPLITS; ++s) {
        float4 w = xp4[(size_t)s * (BB * KDP / 4) + e];
        v.x += w.x; v.y += w.y; v.z += w.z; v.w += w.w;
    }
    ((float4*)x)[e] = v;
}

// ---------------- K3: pairwise exp-L1, 2 k's per block ----------------
// grid (8 i-tiles, 50 k-pairs), block 512 (8 waves). Wave w: j in [w*64, w*64+64).
// xs[j] = 10 floats (k0 d0..4, k1 d0..4) in a 48B row; reads b128+b128+b64.
__global__ __launch_bounds__(512) void pair2k(
    const float* __restrict__ x, float* __restrict__ out)
{
    const int i0 = blockIdx.x * 64;
    const int kp = blockIdx.y;          // k-pair: k0 = 2*kp, k1 = 2*kp+1
    const int t  = threadIdx.x;
    const int lane = t & 63;
    const int w    = t >> 6;

    __shared__ float xs[BB][12];        // 24 KiB
    __shared__ float ps[8][64][2];      // 4 KiB partials

    // fold-free fill: read x[j][kp*10 .. +9] as float2s, fully L2-friendly
    const int kbase = kp * 10;
    #pragma unroll
    for (int it = 0; it < 5; ++it) {
        int e = t + it * 512;           // < 2560
        int j = e / 5;
        int c = e - j * 5;
        float2 f2 = *(const float2*)&x[(size_t)j * KDP + kbase + c * 2];
        *(float2*)&xs[j][c * 2] = f2;
    }
    __syncthreads();

    const int i = i0 + lane;
    const float4 xi0 = *(const float4*)&xs[i][0];
    const float4 xi1 = *(const float4*)&xs[i][4];
    const float2 xi2 = *(const float2*)&xs[i][8];
    const float NEG_LOG2E = -1.4426950408889634f;

    float s0 = 0.f, s1 = 0.f;
    #pragma unroll 4
    for (int jj = 0; jj < 64; ++jj) {
        const int j = (w << 6) + jj;    // uniform across wave -> LDS broadcast
        float4 xj0 = *(const float4*)&xs[j][0];
        float4 xj1 = *(const float4*)&xs[j][4];
        float2 xj2 = *(const float2*)&xs[j][8];
        // k0: d0..d3 in xj0, d4 = xj1.x
        float aa0 = (fabsf(xi0.x - xj0.x) + fabsf(xi0.y - xj0.y))
                  + (fabsf(xi0.z - xj0.z) + fabsf(xi0.w - xj0.w))
                  + fabsf(xi1.x - xj1.x);
        // k1: d0..d2 in xj1.yzw, d3 = xj2.x, d4 = xj2.y
        float aa1 = (fabsf(xi1.y - xj1.y) + fabsf(xi1.z - xj1.z))
                  + (fabsf(xi1.w - xj1.w) + fabsf(xi2.x - xj2.x))
                  + fabsf(xi2.y - xj2.y);
        s0 += __builtin_amdgcn_exp2f(NEG_LOG2E * aa0);
        s1 += __builtin_amdgcn_exp2f(NEG_LOG2E * aa1);
    }

    ps[w][lane][0] = s0;
    ps[w][lane][1] = s1;
    __syncthreads();

    if (t < 128) {
        const int li = t & 63;
        const int kk = t >> 6;
        float v = 0.f;
        #pragma unroll
        for (int q = 0; q < 8; ++q) v += ps[q][li][kk];
        out[(size_t)(i0 + li) * KK + kp * 2 + kk] = v;
    }
}

// ---------------- Fallback: round-1 fused kernel (ws too small) ----------
__global__ __launch_bounds__(1024, 1) void mbd_fused(
    const float* __restrict__ in, const float* __restrict__ T, float* __restrict__ out)
{
    const int k = blockIdx.x;
    const int t = threadIdx.x;
    const int i = t & (BB - 1);
    const int h = t >> 9;

    __shared__ float xk[1024][8];

    float a0 = 0.f, a1 = 0.f, a2 = 0.f, a3 = 0.f, a4 = 0.f;
    const float4* inrow = (const float4*)(in + (size_t)i * FF + (size_t)h * 512);
    const float* Tk = T + 5 * k + (size_t)h * 512 * KD;

    for (int ff = 0; ff < 512; ff += 4) {
        float4 v = inrow[ff >> 2];
        const float* tp = Tk + (size_t)ff * KD;
        a0 = fmaf(v.x, tp[0], a0); a1 = fmaf(v.x, tp[1], a1); a2 = fmaf(v.x, tp[2], a2);
        a3 = fmaf(v.x, tp[3], a3); a4 = fmaf(v.x, tp[4], a4); tp += KD;
        a0 = fmaf(v.y, tp[0], a0); a1 = fmaf(v.y, tp[1], a1); a2 = fmaf(v.y, tp[2], a2);
        a3 = fmaf(v.y, tp[3], a3); a4 = fmaf(v.y, tp[4], a4); tp += KD;
        a0 = fmaf(v.z, tp[0], a0); a1 = fmaf(v.z, tp[1], a1); a2 = fmaf(v.z, tp[2], a2);
        a3 = fmaf(v.z, tp[3], a3); a4 = fmaf(v.z, tp[4], a4); tp += KD;
        a0 = fmaf(v.w, tp[0], a0); a1 = fmaf(v.w, tp[1], a1); a2 = fmaf(v.w, tp[2], a2);
        a3 = fmaf(v.w, tp[3], a3); a4 = fmaf(v.w, tp[4], a4);
    }
    xk[t][0] = a0; xk[t][1] = a1; xk[t][2] = a2; xk[t][3] = a3; xk[t][4] = a4;
    __syncthreads();
    if (t < BB) {
        xk[t][0] += xk[t + BB][0]; xk[t][1] += xk[t + BB][1]; xk[t][2] += xk[t + BB][2];
        xk[t][3] += xk[t + BB][3]; xk[t][4] += xk[t + BB][4];
    }
    __syncthreads();

    const int jg = t >> 9;
    const float4 xiv = *(const float4*)&xk[i][0];
    const float xi4 = xk[i][4];
    const float NEG_LOG2E = -1.4426950408889634f;
    float s0 = 0.f;
    const int j0 = jg << 8;
    for (int jj = 0; jj < 256; ++jj) {
        const int j = j0 + jj;
        float4 xj = *(const float4*)&xk[j][0];
        float xj4 = xk[j][4];
        float aa = (fabsf(xiv.x - xj.x) + fabsf(xiv.y - xj.y))
                 + (fabsf(xiv.z - xj.z) + fabsf(xiv.w - xj.w)) + fabsf(xi4 - xj4);
        s0 += __builtin_amdgcn_exp2f(NEG_LOG2E * aa);
    }
    xk[BB + i][jg] = s0;
    __syncthreads();
    if (t < BB)
        out[(size_t)t * KK + k] = xk[BB + t][0] + xk[BB + t][1];
}

// ---------------- launch ----------------
extern "C" void kernel_launch(void* const* d_in, const int* in_sizes, int n_in,
                              void* d_out, int out_size, void* d_ws, size_t ws_size,
                              hipStream_t stream) {
    const float* in = (const float*)d_in[0];   // [512, 1024]
    const float* T  = (const float*)d_in[1];   // [1024, 500]
    float* out = (float*)d_out;                // [512, 100]

    const size_t xp_bytes = (size_t)SPLITS * BB * KDP * sizeof(float);  // 8 MiB
    const size_t x_bytes  = (size_t)BB * KDP * sizeof(float);           // 1 MiB

    if (ws_size < xp_bytes + x_bytes) {
        mbd_fused<<<KK, 1024, 0, stream>>>(in, T, out);
        return;
    }

    float* xp = (float*)d_ws;
    float* x  = (float*)((char*)d_ws + xp_bytes);

    dim3 g1(BB / 64, KDP / 64, SPLITS);        // 8 x 8 x 8 = 512 blocks
    proj_tile<<<g1, 256, 0, stream>>>(in, T, xp);

    reduce_x<<<(BB * KDP / 4) / 256, 256, 0, stream>>>(xp, x);   // 256 blocks

    dim3 g3(BB / 64, KK / 2);                  // 8 x 50 = 400 blocks
    pair2k<<<g3, 512, 0, stream>>>(x, out);
}

// Round 4
// 35.787 us; speedup vs baseline: 2.4480x; 1.0564x over previous
//
#include <hip/hip_runtime.h>

// MinibatchDiscrimination, three-phase (all fp32):
//   K1 proj_tile : xp[s][i][kd] partial GEMM, split-K 16, reg-double-buffered
//   K2 reduce_t  : xT[kd][i] = log2e * sum_s xp[s][i][kd]   (LDS transpose)
//   K3 pair2k    : out[i,k] = sum_j exp2(-sum_d |xT'-xT'|)   (2 k per block)
//
// inputs [512,1024] f32, T [1024,500] f32, out [512,100] f32.

#define BB 512
#define FF 1024
#define KK 100
#define KD 500
#define KDP 512
#define SPLITS 16
#define FN (FF / SPLITS)     // 64 f per split
#define STEPS (FN / 16)      // 4

#define LOG2E 1.4426950408889634f

// ---------------- K1: register-tiled fp32 GEMM partials ----------------
// grid (8 i-tiles, 8 kd-tiles, 16 splits) = 1024 blocks, block 256.
// Tile 64i x 64kd, per-thread 4x4. Staging double-buffered through registers.
__global__ __launch_bounds__(256, 4) void proj_tile(
    const float* __restrict__ in, const float* __restrict__ T,
    float* __restrict__ xp)
{
    const int i0  = blockIdx.x * 64;
    const int kd0 = blockIdx.y * 64;
    const int s   = blockIdx.z;
    const int t   = threadIdx.x;
    const int tk  = t & 15;
    const int ti  = t >> 4;

    __shared__ float Ads[16][68];   // [f][i], row 272B
    __shared__ float Bds[16][64];   // [f][kd]

    float acc[4][4];
    #pragma unroll
    for (int r = 0; r < 4; ++r)
        #pragma unroll
        for (int c = 0; c < 4; ++c) acc[r][c] = 0.f;

    // staging roles
    const int ia  = t >> 2;               // i row for A staging (0..63)
    const int fqa = t & 3;                // f-quad for A
    const int kb  = t & 63;               // kd lane for B
    const int frb = t >> 6;               // f-quad for B (0..3)
    const int kbc = min(kd0 + kb, KD - 1);

    const float* inb = in + (size_t)(i0 + ia) * FF + s * FN;
    const float* Tb  = T + (size_t)(s * FN) * KD + kbc;

    // prologue loads (step 0)
    float4 av = *(const float4*)&inb[fqa * 4];
    float bv0 = Tb[(size_t)(frb * 4 + 0) * KD];
    float bv1 = Tb[(size_t)(frb * 4 + 1) * KD];
    float bv2 = Tb[(size_t)(frb * 4 + 2) * KD];
    float bv3 = Tb[(size_t)(frb * 4 + 3) * KD];

    for (int step = 0; step < STEPS; ++step) {
        Ads[fqa * 4 + 0][ia] = av.x;
        Ads[fqa * 4 + 1][ia] = av.y;
        Ads[fqa * 4 + 2][ia] = av.z;
        Ads[fqa * 4 + 3][ia] = av.w;
        Bds[frb * 4 + 0][kb] = bv0;
        Bds[frb * 4 + 1][kb] = bv1;
        Bds[frb * 4 + 2][kb] = bv2;
        Bds[frb * 4 + 3][kb] = bv3;
        __syncthreads();

        if (step + 1 < STEPS) {          // prefetch next step; hides under FMAs
            const int fo = (step + 1) * 16;
            av  = *(const float4*)&inb[fo + fqa * 4];
            bv0 = Tb[(size_t)(fo + frb * 4 + 0) * KD];
            bv1 = Tb[(size_t)(fo + frb * 4 + 1) * KD];
            bv2 = Tb[(size_t)(fo + frb * 4 + 2) * KD];
            bv3 = Tb[(size_t)(fo + frb * 4 + 3) * KD];
        }

        #pragma unroll
        for (int f = 0; f < 16; ++f) {
            float4 a = *(const float4*)&Ads[f][ti * 4];
            float4 b = *(const float4*)&Bds[f][tk * 4];
            float ar[4] = {a.x, a.y, a.z, a.w};
            float br[4] = {b.x, b.y, b.z, b.w};
            #pragma unroll
            for (int r = 0; r < 4; ++r)
                #pragma unroll
                for (int c = 0; c < 4; ++c)
                    acc[r][c] = fmaf(ar[r], br[c], acc[r][c]);
        }
        if (step + 1 < STEPS) __syncthreads();
    }

    #pragma unroll
    for (int r = 0; r < 4; ++r) {
        float4 v = {acc[r][0], acc[r][1], acc[r][2], acc[r][3]};
        *(float4*)&xp[((size_t)s * BB + i0 + ti * 4 + r) * KDP + kd0 + tk * 4] = v;
    }
}

// ---------------- K2: fold splits + transpose + pre-scale by log2e --------
// grid (16 kd-tiles, 16 i-tiles) = 256 blocks, block 256. Tile 32i x 32kd.
__global__ __launch_bounds__(256) void reduce_t(
    const float* __restrict__ xp, float* __restrict__ xT)
{
    const int kd0 = blockIdx.x * 32;
    const int i0  = blockIdx.y * 32;
    const int t   = threadIdx.x;
    const int c4  = t & 7;          // float4 col within tile
    const int rr  = t >> 3;         // row within tile (0..31)

    __shared__ float tile[32][33];

    const float4* p = (const float4*)xp + ((size_t)(i0 + rr) * KDP + kd0) / 4 + c4;
    float4 v = {0.f, 0.f, 0.f, 0.f};
    #pragma unroll
    for (int s = 0; s < SPLITS; ++s) {
        float4 w = p[(size_t)s * (BB * KDP / 4)];
        v.x += w.x; v.y += w.y; v.z += w.z; v.w += w.w;
    }
    tile[rr][c4 * 4 + 0] = v.x;
    tile[rr][c4 * 4 + 1] = v.y;
    tile[rr][c4 * 4 + 2] = v.z;
    tile[rr][c4 * 4 + 3] = v.w;
    __syncthreads();

    // out row = kd, cols = i; tile[c'][r'] = x[i0+c'][kd0+r']
    float4 o = { tile[c4 * 4 + 0][rr] * LOG2E,
                 tile[c4 * 4 + 1][rr] * LOG2E,
                 tile[c4 * 4 + 2][rr] * LOG2E,
                 tile[c4 * 4 + 3][rr] * LOG2E };
    *(float4*)&xT[(size_t)(kd0 + rr) * BB + i0 + c4 * 4] = o;
}

// ---------------- K3: pairwise exp2(-L1), 2 k's per block ----------------
// grid (8 i-tiles, 50 k-pairs) = 400 blocks, block 512 (8 waves).
// xs[j] = 10 pre-scaled floats (k0 d0..4, k1 d0..4), 48B rows.
__global__ __launch_bounds__(512) void pair2k(
    const float* __restrict__ xT, float* __restrict__ out)
{
    const int i0 = blockIdx.x * 64;
    const int kp = blockIdx.y;
    const int t  = threadIdx.x;
    const int lane = t & 63;
    const int w    = t >> 6;

    __shared__ float xs[BB][12];     // 24 KiB
    __shared__ float ps[8][64][2];   // 4 KiB

    // fill: 10 coalesced row reads from xT (each 512 contiguous floats)
    const int kbase = kp * 10;
    #pragma unroll
    for (int c = 0; c < 10; ++c)
        xs[t][c] = xT[(size_t)(kbase + c) * BB + t];
    __syncthreads();

    const int i = i0 + lane;
    const float4 xi0 = *(const float4*)&xs[i][0];
    const float4 xi1 = *(const float4*)&xs[i][4];
    const float2 xi2 = *(const float2*)&xs[i][8];

    float s00 = 0.f, s01 = 0.f, s10 = 0.f, s11 = 0.f;
    #pragma unroll 2
    for (int jj = 0; jj < 64; jj += 2) {
        {
            const int j = (w << 6) + jj;         // uniform -> LDS broadcast
            float4 xj0 = *(const float4*)&xs[j][0];
            float4 xj1 = *(const float4*)&xs[j][4];
            float2 xj2 = *(const float2*)&xs[j][8];
            float aa0 = (fabsf(xi0.x - xj0.x) + fabsf(xi0.y - xj0.y))
                      + (fabsf(xi0.z - xj0.z) + fabsf(xi0.w - xj0.w))
                      + fabsf(xi1.x - xj1.x);
            float aa1 = (fabsf(xi1.y - xj1.y) + fabsf(xi1.z - xj1.z))
                      + (fabsf(xi1.w - xj1.w) + fabsf(xi2.x - xj2.x))
                      + fabsf(xi2.y - xj2.y);
            s00 += __builtin_amdgcn_exp2f(-aa0);
            s10 += __builtin_amdgcn_exp2f(-aa1);
        }
        {
            const int j = (w << 6) + jj + 1;
            float4 xj0 = *(const float4*)&xs[j][0];
            float4 xj1 = *(const float4*)&xs[j][4];
            float2 xj2 = *(const float2*)&xs[j][8];
            float aa0 = (fabsf(xi0.x - xj0.x) + fabsf(xi0.y - xj0.y))
                      + (fabsf(xi0.z - xj0.z) + fabsf(xi0.w - xj0.w))
                      + fabsf(xi1.x - xj1.x);
            float aa1 = (fabsf(xi1.y - xj1.y) + fabsf(xi1.z - xj1.z))
                      + (fabsf(xi1.w - xj1.w) + fabsf(xi2.x - xj2.x))
                      + fabsf(xi2.y - xj2.y);
            s01 += __builtin_amdgcn_exp2f(-aa0);
            s11 += __builtin_amdgcn_exp2f(-aa1);
        }
    }

    ps[w][lane][0] = s00 + s01;
    ps[w][lane][1] = s10 + s11;
    __syncthreads();

    if (t < 128) {
        const int li = t & 63;
        const int kk = t >> 6;
        float v = 0.f;
        #pragma unroll
        for (int q = 0; q < 8; ++q) v += ps[q][li][kk];
        out[(size_t)(i0 + li) * KK + kp * 2 + kk] = v;
    }
}

// ---------------- Fallback (ws too small): round-1 fused ----------------
__global__ __launch_bounds__(1024, 1) void mbd_fused(
    const float* __restrict__ in, const float* __restrict__ T, float* __restrict__ out)
{
    const int k = blockIdx.x;
    const int t = threadIdx.x;
    const int i = t & (BB - 1);
    const int h = t >> 9;

    __shared__ float xk[1024][8];

    float a0 = 0.f, a1 = 0.f, a2 = 0.f, a3 = 0.f, a4 = 0.f;
    const float4* inrow = (const float4*)(in + (size_t)i * FF + (size_t)h * 512);
    const float* Tk = T + 5 * k + (size_t)h * 512 * KD;

    for (int ff = 0; ff < 512; ff += 4) {
        float4 v = inrow[ff >> 2];
        const float* tp = Tk + (size_t)ff * KD;
        a0 = fmaf(v.x, tp[0], a0); a1 = fmaf(v.x, tp[1], a1); a2 = fmaf(v.x, tp[2], a2);
        a3 = fmaf(v.x, tp[3], a3); a4 = fmaf(v.x, tp[4], a4); tp += KD;
        a0 = fmaf(v.y, tp[0], a0); a1 = fmaf(v.y, tp[1], a1); a2 = fmaf(v.y, tp[2], a2);
        a3 = fmaf(v.y, tp[3], a3); a4 = fmaf(v.y, tp[4], a4); tp += KD;
        a0 = fmaf(v.z, tp[0], a0); a1 = fmaf(v.z, tp[1], a1); a2 = fmaf(v.z, tp[2], a2);
        a3 = fmaf(v.z, tp[3], a3); a4 = fmaf(v.z, tp[4], a4); tp += KD;
        a0 = fmaf(v.w, tp[0], a0); a1 = fmaf(v.w, tp[1], a1); a2 = fmaf(v.w, tp[2], a2);
        a3 = fmaf(v.w, tp[3], a3); a4 = fmaf(v.w, tp[4], a4);
    }
    xk[t][0] = a0; xk[t][1] = a1; xk[t][2] = a2; xk[t][3] = a3; xk[t][4] = a4;
    __syncthreads();
    if (t < BB) {
        xk[t][0] += xk[t + BB][0]; xk[t][1] += xk[t + BB][1]; xk[t][2] += xk[t + BB][2];
        xk[t][3] += xk[t + BB][3]; xk[t][4] += xk[t + BB][4];
    }
    __syncthreads();

    const int jg = t >> 9;
    const float4 xiv = *(const float4*)&xk[i][0];
    const float xi4 = xk[i][4];
    const float NEG_LOG2E = -1.4426950408889634f;
    float s0 = 0.f;
    const int j0 = jg << 8;
    for (int jj = 0; jj < 256; ++jj) {
        const int j = j0 + jj;
        float4 xj = *(const float4*)&xk[j][0];
        float xj4 = xk[j][4];
        float aa = (fabsf(xiv.x - xj.x) + fabsf(xiv.y - xj.y))
                 + (fabsf(xiv.z - xj.z) + fabsf(xiv.w - xj.w)) + fabsf(xi4 - xj4);
        s0 += __builtin_amdgcn_exp2f(NEG_LOG2E * aa);
    }
    xk[BB + i][jg] = s0;
    __syncthreads();
    if (t < BB)
        out[(size_t)t * KK + k] = xk[BB + t][0] + xk[BB + t][1];
}

// ---------------- launch ----------------
extern "C" void kernel_launch(void* const* d_in, const int* in_sizes, int n_in,
                              void* d_out, int out_size, void* d_ws, size_t ws_size,
                              hipStream_t stream) {
    const float* in = (const float*)d_in[0];   // [512, 1024]
    const float* T  = (const float*)d_in[1];   // [1024, 500]
    float* out = (float*)d_out;                // [512, 100]

    const size_t xp_bytes = (size_t)SPLITS * BB * KDP * sizeof(float);  // 16 MiB
    const size_t x_bytes  = (size_t)BB * KDP * sizeof(float);           // 1 MiB

    if (ws_size < xp_bytes + x_bytes) {
        mbd_fused<<<KK, 1024, 0, stream>>>(in, T, out);
        return;
    }

    float* xp = (float*)d_ws;
    float* xT = (float*)((char*)d_ws + xp_bytes);

    dim3 g1(BB / 64, KDP / 64, SPLITS);        // 8 x 8 x 16 = 1024 blocks
    proj_tile<<<g1, 256, 0, stream>>>(in, T, xp);

    dim3 g2(KDP / 32, BB / 32);                // 16 x 16 = 256 blocks
    reduce_t<<<g2, 256, 0, stream>>>(xp, xT);

    dim3 g3(BB / 64, KK / 2);                  // 8 x 50 = 400 blocks
    pair2k<<<g3, 512, 0, stream>>>(xT, out);
}